// Round 3
// baseline (47.158 us; speedup 1.0000x reference)
//
#include <hip/hip_runtime.h>
#include <stdint.h>

// IAF spiking layer: data (B*T, F) fp32, B=32, T=1024, F=1024.
// One thread per (b,f) chain; t strictly sequential. 32768 threads total
// (2 waves/CU) -> latency hiding must come from a guaranteed-deep
// global_load_lds pipeline with counted vmcnt waits (never 0).
//
// R2 changes vs R1:
//  - nontemporal output stores: output is never re-read; nt keeps the
//    128 MiB input resident in the 256 MiB L3 across graph replays
//    (R1 counters showed writes evicting half the input -> 67 MB refetch).
//  - prefetch depth 3 -> 4 via reordered body {wait, compute+store,
//    issue L(c+4)}: ops-after-L(c) = (P-1)*(16 st + 4 ld) = 60 <= 63.
//
// vmcnt accounting (4 load-insts + 16 store-insts per chunk, order pinned
// by sched_barrier(0) + asm memory clobbers):
//   prologue waits: 12, 28, 44; steady: 60; tail: 56, 52, 48.

constexpr int T = 1024;
constexpr int F = 1024;
constexpr int DEPTH = 16;                 // t-steps per chunk
constexpr int CHUNK_FLOATS = DEPTH * 64;  // 1024 floats = 4 KB per buffer

#define WAITVM(N) asm volatile("s_waitcnt vmcnt(" #N ")" ::: "memory")

__global__ __launch_bounds__(64) void iaf_kernel(const float* __restrict__ x,
                                                 float* __restrict__ out) {
    __shared__ float lds[4 * CHUNK_FLOATS];   // 16 KB ring (4 buffers)

    const int lane = threadIdx.x;             // 0..63
    const int b = blockIdx.x >> 4;            // 32 batch rows
    const int f0 = (blockIdx.x & 15) * 64;    // feature block base

    const size_t base = ((size_t)b * T) * F + f0;
    const float* __restrict__ p = x + base;   // row t at p + t*F
    float* __restrict__ q = out + base + lane;

    // per-lane source mapping for the 16B global_load_lds:
    // instr r (r=0..3) of chunk k covers row k*16 + r*4 + (lane>>4),
    // bytes [(lane&15)*16, +16). LDS dest = base + lane*16 (hardware,
    // linear) == row-major [16][64] float tile.
    const int lrow = lane >> 4;
    const int lcol = (lane & 15) * 4;

    float s = 0.0f, a = 0.0f;

    auto issue_chunk = [&](int k) {
        // all ds_reads of the buffer being overwritten were consumed during
        // the preceding compute; this drain is free and closes the ring
        // reuse hazard (L(k) targets buffer (k&3) just computed from).
        asm volatile("s_waitcnt lgkmcnt(0)" ::: "memory");
        __builtin_amdgcn_sched_barrier(0);
        float* lb = &lds[(k & 3) * CHUNK_FLOATS];
#pragma unroll
        for (int r = 0; r < 4; ++r) {
            const float* gsrc = p + (size_t)(k * DEPTH + r * 4 + lrow) * F + lcol;
            __builtin_amdgcn_global_load_lds(
                (const __attribute__((address_space(1))) void*)gsrc,
                (__attribute__((address_space(3))) void*)(lb + r * 256),
                16, 0, 0);
        }
        __builtin_amdgcn_sched_barrier(0);
    };

    auto compute_chunk = [&](int k) {
        const float* lb = &lds[(k & 3) * CHUNK_FLOATS];
        float xv[DEPTH];
#pragma unroll
        for (int i = 0; i < DEPTH; ++i) xv[i] = lb[i * 64 + lane];
#pragma unroll
        for (int i = 0; i < DEPTH; ++i) {
            // exact reference op order (bit-exact floor/relu feedback):
            s = (xv[i] + s) - a;
            s = fmaxf(s + 1.0f, 0.0f) - 1.0f;    // relu(s - (-1)) + (-1)
            a = (s > 0.0f) ? floorf(s) : 0.0f;
            // nt store: don't let output writes evict the input from L3
            __builtin_nontemporal_store(a, &q[(size_t)(k * DEPTH + i) * F]);
        }
        __builtin_amdgcn_sched_barrier(0);
    };

    // prologue: 4 chunks in flight
    issue_chunk(0);
    issue_chunk(1);
    issue_chunk(2);
    issue_chunk(3);

    // peeled head (exact outstanding-op counts after L(c)):
    WAITVM(12); compute_chunk(0); issue_chunk(4);
    WAITVM(28); compute_chunk(1); issue_chunk(5);
    WAITVM(44); compute_chunk(2); issue_chunk(6);

    // steady state: ops after L(c) = 3*(16 st) + 3*(4 ld) = 60
    for (int c = 3; c <= 60; ++c) {
        WAITVM(60);
        compute_chunk(c);
        if (c <= 59) issue_chunk(c + 4);
    }

    // tail (exact counts: 56, 52, 48)
    WAITVM(56); compute_chunk(61);
    WAITVM(52); compute_chunk(62);
    WAITVM(48); compute_chunk(63);
}

extern "C" void kernel_launch(void* const* d_in, const int* in_sizes, int n_in,
                              void* d_out, int out_size, void* d_ws, size_t ws_size,
                              hipStream_t stream) {
    const float* x = (const float*)d_in[0];
    float* out = (float*)d_out;
    // 512 blocks x 64 threads = 32768 chains (one per (b,f)); 2 waves/CU.
    iaf_kernel<<<dim3(512), dim3(64), 0, stream>>>(x, out);
}